// Round 8
// baseline (730.335 us; speedup 1.0000x reference)
//
#include <hip/hip_runtime.h>
#include <stdint.h>

// Problem constants
#define B_   2
#define S_   2048
#define D_   1024
#define H_   16
#define DK_  64
#define DFF_ 4096
#define M_   (B_ * S_)   // 4096 rows total
#define QKV_LD 3072      // fused qkv row stride

typedef unsigned short u16;
typedef unsigned int   u32;
typedef __attribute__((ext_vector_type(8))) short short8;  // 8 bf16 (4 VGPRs)
typedef __attribute__((ext_vector_type(4))) float f32x4;   // MFMA C/D

// ---------- bf16 <-> f32 helpers ----------
__device__ __forceinline__ float b2f(u16 u) {
  union { u32 i; float f; } z; z.i = ((u32)u) << 16; return z.f;
}
__device__ __forceinline__ u16 f2b(float f) {
  union { float f; u32 i; } z; z.f = f;
  u32 x = z.i;
  u32 r = (x + 0x7fffu + ((x >> 16) & 1u)) >> 16;
  return (u16)r;
}
__device__ __forceinline__ void load4(const float* p, float* f) {
  float4 v = *(const float4*)p;
  f[0] = v.x; f[1] = v.y; f[2] = v.z; f[3] = v.w;
}
__device__ __forceinline__ void load4(const u16* p, float* f) {
  uint2 v = *(const uint2*)p;
  f[0] = b2f(v.x & 0xffffu); f[1] = b2f(v.x >> 16);
  f[2] = b2f(v.y & 0xffffu); f[3] = b2f(v.y >> 16);
}
__device__ __forceinline__ void tstore(float* p, float v) { *p = v; }
__device__ __forceinline__ void tstore(u16* p, float v)   { *p = f2b(v); }

// async global->LDS, 16 B per lane (dest = wave-uniform base + lane*16)
__device__ __forceinline__ void gld_lds16(const void* g, void* l) {
  __builtin_amdgcn_global_load_lds(
      (const __attribute__((address_space(1))) void*)g,
      (__attribute__((address_space(3))) void*)l, 16, 0, 0);
}

// ---------- m97-style MFMA GEMM: C = (A @ Wt^T + bias)*osc (+ReLU)(+res) ----
// A: bf16 [M][K] k-contig. Wt: bf16 [N][K] k-contig (pre-transposed weight).
// Tile BM x 128, BK=32, 256 threads = 4 waves (2x2), wave tile (BM/2) x 64.
// MFMA layouts: A[m=lane&15][k=quad*8+j], B[n=lane&15][k=quad*8+j],
// D[row=quad*4+r][col=lane&15].
// QKV=true: N spans 3 weight segments of 1024; per-block bias/scale select;
// bias indexed with SEGMENT-LOCAL column (col0 & 1023).
template<int BM, bool RELU, bool RES, bool BIAS, bool QKV, typename TO>
__global__ __launch_bounds__(256)
void gemm_bf16(const u16* __restrict__ A, const u16* __restrict__ Wt,
               const float* __restrict__ bias0, const float* __restrict__ bias1,
               const float* __restrict__ bias2, const float* __restrict__ res,
               TO* __restrict__ C, int M, int N, int K)
{
  constexpr int WM = BM / 2;     // wave M extent
  constexpr int MI = WM / 16;    // A-frags per wave (4 or 2)
  __shared__ u16 As[BM][32];
  __shared__ u16 Bs[128][32];

  const int tid  = threadIdx.x;
  const int wave = tid >> 6;
  const int lane = tid & 63;
  const int lo16 = lane & 15;
  const int quad = lane >> 4;
  const int row0 = blockIdx.y * BM;
  const int col0 = blockIdx.x * 128;
  const int mb   = (wave & 1) * WM;
  const int nb   = (wave >> 1) * 64;

  const float* bias = bias0;
  float osc = 1.0f;
  if (QKV) {
    const int seg = col0 >> 10;              // block fully inside one segment
    bias = (seg == 0) ? bias0 : (seg == 1 ? bias1 : bias2);
    if (seg == 0) osc = 0.125f;              // 1/sqrt(dk) folded into q
  }
  const int bc0 = QKV ? (col0 & 1023) : col0;  // segment-local bias column

  f32x4 acc[MI][4];
#pragma unroll
  for (int i = 0; i < MI; ++i)
#pragma unroll
    for (int j = 0; j < 4; ++j) acc[i][j] = (f32x4){0.f, 0.f, 0.f, 0.f};

  const int s_row = tid >> 2;          // 0..63
  const int s_ch  = (tid & 3) * 8;     // bf16 elems
  const u16* gA = A  + (size_t)(row0 + s_row) * K + s_ch;
  const u16* gB = Wt + (size_t)(col0 + s_row) * K + s_ch;

  for (int k0 = 0; k0 < K; k0 += 32) {
    gld_lds16(gA, &As[s_row][s_ch]);
    if constexpr (BM == 128)
      gld_lds16(gA + (size_t)64 * K, &As[s_row + (BM == 128 ? 64 : 0)][s_ch]);
    gld_lds16(gB, &Bs[s_row][s_ch]);
    gld_lds16(gB + (size_t)64 * K, &Bs[s_row + 64][s_ch]);
    gA += 32; gB += 32;
    __syncthreads();

    short8 af[MI], bf[4];
#pragma unroll
    for (int mi = 0; mi < MI; ++mi)
      af[mi] = *(const short8*)&As[mb + mi * 16 + lo16][quad * 8];
#pragma unroll
    for (int ni = 0; ni < 4; ++ni)
      bf[ni] = *(const short8*)&Bs[nb + ni * 16 + lo16][quad * 8];
#pragma unroll
    for (int mi = 0; mi < MI; ++mi)
#pragma unroll
      for (int ni = 0; ni < 4; ++ni)
        acc[mi][ni] = __builtin_amdgcn_mfma_f32_16x16x32_bf16(af[mi], bf[ni], acc[mi][ni], 0, 0, 0);
    __syncthreads();
  }

  // epilogue
  float bv[4];
#pragma unroll
  for (int ni = 0; ni < 4; ++ni)
    bv[ni] = BIAS ? bias[bc0 + nb + ni * 16 + lo16] : 0.f;
#pragma unroll
  for (int mi = 0; mi < MI; ++mi) {
#pragma unroll
    for (int ni = 0; ni < 4; ++ni) {
      const int col = col0 + nb + ni * 16 + lo16;
#pragma unroll
      for (int r = 0; r < 4; ++r) {
        const int row = row0 + mb + mi * 16 + quad * 4 + r;
        float vv = (acc[mi][ni][r] + bv[ni]) * osc;
        if (RELU) vv = fmaxf(vv, 0.f);
        if (RES)  vv += res[(size_t)row * N + col];
        tstore(C + (size_t)row * N + col, vv);
      }
    }
  }
}

// ---------- elementwise fp32 -> bf16 ----------
__global__ __launch_bounds__(256)
void cvt_f2b(const float* __restrict__ in, u16* __restrict__ out)
{
  const size_t i = ((size_t)blockIdx.x * 256 + threadIdx.x) * 8;
  float4 a = *(const float4*)(in + i);
  float4 b = *(const float4*)(in + i + 4);
  uint4 o;
  o.x = (u32)f2b(a.x) | ((u32)f2b(a.y) << 16);
  o.y = (u32)f2b(a.z) | ((u32)f2b(a.w) << 16);
  o.z = (u32)f2b(b.x) | ((u32)f2b(b.y) << 16);
  o.w = (u32)f2b(b.z) | ((u32)f2b(b.w) << 16);
  *(uint4*)(out + i) = o;
}

// ---------- bf16 partial merge: out = p0 + p1 (bf16) ----------
__global__ __launch_bounds__(256)
void merge_b16(const u16* __restrict__ p0, const u16* __restrict__ p1,
               u16* __restrict__ out)
{
  const size_t i = ((size_t)blockIdx.x * 256 + threadIdx.x) * 8;
  uint4 a = *(const uint4*)(p0 + i);
  uint4 b = *(const uint4*)(p1 + i);
  uint4 o;
  const u32* ap = (const u32*)&a;
  const u32* bp = (const u32*)&b;
  u32* op = (u32*)&o;
#pragma unroll
  for (int j = 0; j < 4; ++j) {
    float lo = b2f((u16)(ap[j] & 0xffffu)) + b2f((u16)(bp[j] & 0xffffu));
    float hi = b2f((u16)(ap[j] >> 16))     + b2f((u16)(bp[j] >> 16));
    op[j] = (u32)f2b(lo) | ((u32)f2b(hi) << 16);
  }
  *(uint4*)(out + i) = o;
}

// ---------- fp32 [R][C] -> bf16 transposed [C][R] (64x64 tiles) ----------
__global__ __launch_bounds__(256)
void transpose_f2b(const float* __restrict__ in, u16* __restrict__ out,
                   int ld_in, int ld_out)
{
  __shared__ u16 tile[64][68];
  const int t  = threadIdx.x;
  const int r0 = blockIdx.x * 64;
  const int c0 = blockIdx.y * 64;
  const int rr = t >> 4;            // 0..15
  const int cc = (t & 15) * 4;      // 0..60
#pragma unroll
  for (int rep = 0; rep < 4; ++rep) {
    float4 v = *(const float4*)(in + (size_t)(r0 + rr + rep * 16) * ld_in + c0 + cc);
    tile[rr + rep * 16][cc + 0] = f2b(v.x);
    tile[rr + rep * 16][cc + 1] = f2b(v.y);
    tile[rr + rep * 16][cc + 2] = f2b(v.z);
    tile[rr + rep * 16][cc + 3] = f2b(v.w);
  }
  __syncthreads();
#pragma unroll
  for (int rep = 0; rep < 4; ++rep) {
    const int dr = rr + rep * 16;   // local c
    uint2 o;
    o.x = (u32)tile[cc + 0][dr] | ((u32)tile[cc + 1][dr] << 16);
    o.y = (u32)tile[cc + 2][dr] | ((u32)tile[cc + 3][dr] << 16);
    *(uint2*)(out + (size_t)(c0 + dr) * ld_out + r0 + cc) = o;
  }
}

// ---------- bf16 transpose with strides (for V -> Vt) ----------
__global__ __launch_bounds__(256)
void transpose_bf16(const u16* __restrict__ in, u16* __restrict__ out,
                    int ld_in, int ld_out)
{
  __shared__ u16 tile[64][68];
  const int t  = threadIdx.x;
  const int r0 = blockIdx.x * 64;   // token dim
  const int c0 = blockIdx.y * 64;   // feature dim
  const int rr = t >> 4;
  const int cc = (t & 15) * 4;
#pragma unroll
  for (int rep = 0; rep < 4; ++rep) {
    uint2 vv = *(const uint2*)(in + (size_t)(r0 + rr + rep * 16) * ld_in + c0 + cc);
    *(uint2*)&tile[rr + rep * 16][cc] = vv;
  }
  __syncthreads();
#pragma unroll
  for (int rep = 0; rep < 4; ++rep) {
    const int dr = rr + rep * 16;
    uint2 o;
    o.x = (u32)tile[cc + 0][dr] | ((u32)tile[cc + 1][dr] << 16);
    o.y = (u32)tile[cc + 2][dr] | ((u32)tile[cc + 3][dr] << 16);
    *(uint2*)(out + (size_t)(c0 + dr) * ld_out + r0 + cc) = o;
  }
}

// scale a bf16x8 fragment elementwise by rv[0..7] (f32), repack bf16 (RHU)
__device__ __forceinline__ short8 scale8(short8 a, f32x4 r0, f32x4 r1) {
  const u32* ap = (const u32*)&a;
  short8 o;
  u32* op = (u32*)&o;
#pragma unroll
  for (int i = 0; i < 4; ++i) {
    union { u32 u; float f; } lo, hi;
    lo.u = ap[i] << 16;
    hi.u = ap[i] & 0xffff0000u;
    float rl = (i < 2) ? r0[2 * i]     : r1[2 * i - 4];
    float rh = (i < 2) ? r0[2 * i + 1] : r1[2 * i - 3];
    lo.f *= rl;
    hi.f *= rh;
    op[i] = ((lo.u + 0x8000u) >> 16) | ((hi.u + 0x8000u) & 0xffff0000u);
  }
  return o;
}

// ---------- MFMA attention v6: v4 geometry + reg-prefetch pipeline ----------
// Round-6 v4 (242 us, best) geometry: grid 256 = 4 groups (batch x t-half)
// x 64 q-tiles, 512 thr (8 waves), 1 block/CU, QBLK=32.
// v4's stall was 2 barriers/step with phase-A K loads (L2 ~200-900 cyc)
// latency-exposed. v6 pipeline (math bit-identical to v4):
//   per step: (1) issue K(s+1) loads -> 64 VGPRs, (2) phase B(s) MFMAs/Vt
//   loads hide that latency, (3) phase A(s+1) from regs -> Ws/Rs[buf^1],
//   (4) ONE barrier. Ws/Rs double-buffered: LDS = 2x(64+8) KB = 144 KB.
// VGPR ~290 (qf 128 + kf 64 + acc 64 + temps): fine at 2 waves/SIMD.
// Epilogue: bf16 partial ctx per t-half; merged by merge_b16.
__global__ __launch_bounds__(512, 2)
void attention_mfma(const u16* __restrict__ q, const u16* __restrict__ k,
                    const u16* __restrict__ vt, u16* __restrict__ partial)
{
  __shared__ __align__(16) u16 Ws[2][16][32][64];   // 2 x 64 KB (e, bf16)
  __shared__ __align__(16) float Rs[2][32][64];     // 2 x  8 KB (rinv, f32)

  const int tid  = threadIdx.x;
  const int wave = tid >> 6;
  const int lane = tid & 63;
  const int lo16 = lane & 15;
  const int quad = lane >> 4;

  const int p     = blockIdx.x;
  const int g     = (p & 7) >> 1;          // group: batch x t-half
  const int batch = g >> 1;
  const int half  = g & 1;
  const int qt    = ((p >> 3) << 1) | (p & 1);   // 0..63
  const int qrow0 = batch * S_ + qt * 32;
  const int tbase = half * 1024;

  const int qg = wave >> 2;                // 0..1: q-group (16 rows)
  const int tg = wave & 3;                 // 0..3: t-group (16 tokens)
  const int h0 = wave * 2;                 // phase-B heads

  // ---- load Q fragments once (16 heads x 2 K-slices = 128 VGPR) ----
  const u16* qrow = q + (size_t)(qrow0 + qg * 16 + lo16) * QKV_LD + quad * 8;
  short8 qf[32];
#pragma unroll
  for (int h = 0; h < 16; ++h) {
    qf[2 * h]     = *(const short8*)(qrow + h * 64);
    qf[2 * h + 1] = *(const short8*)(qrow + h * 64 + 32);
  }

  f32x4 acc[2][2][4];                      // [hh][qg][dt]
#pragma unroll
  for (int a = 0; a < 2; ++a)
#pragma unroll
    for (int b = 0; b < 2; ++b)
#pragma unroll
      for (int c = 0; c < 4; ++c) acc[a][b][c] = (f32x4){0.f, 0.f, 0.f, 0.f};

  const u16* kbase  = k + (size_t)(batch * S_ + tbase + tg * 16 + lo16) * QKV_LD + quad * 8;
  const u16* vbase0 = vt + (size_t)batch * S_ + tbase + quad * 8;

  // swizzled phase-A write slots (per r)
  int pos_r[4], qabs_r[4];
#pragma unroll
  for (int r = 0; r < 4; ++r) {
    qabs_r[r] = qg * 16 + quad * 4 + r;
    pos_r[r]  = (tg * 16 + lo16) ^ ((qabs_r[r] & 7) << 3);
  }

  // ---- prologue: phase A(0) -> buf 0 (loads exposed once) ----
  {
    const u16* krow = kbase;
    float ssum[4] = {0.f, 0.f, 0.f, 0.f};
#pragma unroll
    for (int h = 0; h < 16; ++h) {
      short8 b0 = *(const short8*)(krow + h * 64);
      short8 b1 = *(const short8*)(krow + h * 64 + 32);
      f32x4 sg = (f32x4){0.f, 0.f, 0.f, 0.f};
      sg = __builtin_amdgcn_mfma_f32_16x16x32_bf16(qf[2 * h],     b0, sg, 0, 0, 0);
      sg = __builtin_amdgcn_mfma_f32_16x16x32_bf16(qf[2 * h + 1], b1, sg, 0, 0, 0);
#pragma unroll
      for (int r = 0; r < 4; ++r) {
        union { float f; u32 u; } e;
        e.f = __expf(sg[r]);               // no max: |S| <~ 3 by construction
        ssum[r] += e.f;
        Ws[0][h][qabs_r[r]][pos_r[r]] = (u16)((e.u + 0x8000u) >> 16);
      }
    }
#pragma unroll
    for (int r = 0; r < 4; ++r)
      Rs[0][qabs_r[r]][pos_r[r]] = 1.0f / ssum[r];
  }
  __syncthreads();

  for (int s = 0; s < 16; ++s) {
    const int buf = s & 1;

    // (1) issue next-step K loads into registers (latency hides under B)
    short8 kf[32];
    if (s < 15) {
      const u16* krow = kbase + (size_t)((s + 1) * 64) * QKV_LD;
#pragma unroll
      for (int h = 0; h < 16; ++h) {
        kf[2 * h]     = *(const short8*)(krow + h * 64);
        kf[2 * h + 1] = *(const short8*)(krow + h * 64 + 32);
      }
    }

    // (2) phase B(s): ctx += (e * rinv) @ V from buf
#pragma unroll
    for (int kc = 0; kc < 2; ++kc) {
      const int ksw = (kc * 32 + quad * 8) ^ ((lo16 & 7) << 3);
      f32x4 rv0a = *(const f32x4*)&Rs[buf][lo16][ksw];
      f32x4 rv0b = *(const f32x4*)&Rs[buf][lo16][ksw + 4];
      f32x4 rv1a = *(const f32x4*)&Rs[buf][16 + lo16][ksw];
      f32x4 rv1b = *(const f32x4*)&Rs[buf][16 + lo16][ksw + 4];
#pragma unroll
      for (int hh = 0; hh < 2; ++hh) {
        short8 sw0 = scale8(*(const short8*)&Ws[buf][h0 + hh][lo16][ksw],      rv0a, rv0b);
        short8 sw1 = scale8(*(const short8*)&Ws[buf][h0 + hh][16 + lo16][ksw], rv1a, rv1b);
#pragma unroll
        for (int dt = 0; dt < 4; ++dt) {
          short8 bv = *(const short8*)(vbase0 +
              (size_t)((h0 + hh) * 64 + dt * 16 + lo16) * M_ + s * 64 + kc * 32);
          acc[hh][0][dt] = __builtin_amdgcn_mfma_f32_16x16x32_bf16(sw0, bv, acc[hh][0][dt], 0, 0, 0);
          acc[hh][1][dt] = __builtin_amdgcn_mfma_f32_16x16x32_bf16(sw1, bv, acc[hh][1][dt], 0, 0, 0);
        }
      }
    }

    // (3) phase A(s+1) from prefetched registers -> buf^1
    if (s < 15) {
      float ssum[4] = {0.f, 0.f, 0.f, 0.f};
#pragma unroll
      for (int h = 0; h < 16; ++h) {
        f32x4 sg = (f32x4){0.f, 0.f, 0.f, 0.f};
        sg = __builtin_amdgcn_mfma_f32_16x16x32_bf16(qf[2 * h],     kf[2 * h],     sg, 0, 0, 0);
        sg = __builtin_amdgcn_mfma_f32_16x16x32_bf16(qf[2 * h + 1], kf[2 * h + 1], sg, 0, 0, 0);
#pragma unroll
        for (int r = 0; r < 4; ++r) {
          union { float f; u32 u; } e;
          e.f = __expf(sg[r]);
          ssum[r] += e.f;
          Ws[buf ^ 1][h][qabs_r[r]][pos_r[r]] = (u16)((e.u + 0x8000u) >> 16);
        }
      }
#pragma unroll
      for (int r = 0; r < 4; ++r)
        Rs[buf ^ 1][qabs_r[r]][pos_r[r]] = 1.0f / ssum[r];
    }

    // (4) one barrier: publishes buf^1, releases buf
    __syncthreads();
  }

  // epilogue: bf16 partial ctx (each element written by exactly one block)
  u16* pb = partial + (size_t)half * M_ * D_;
#pragma unroll
  for (int hh = 0; hh < 2; ++hh)
#pragma unroll
    for (int qgg = 0; qgg < 2; ++qgg)
#pragma unroll
      for (int dt = 0; dt < 4; ++dt)
#pragma unroll
        for (int r = 0; r < 4; ++r) {
          const int row = qrow0 + qgg * 16 + quad * 4 + r;
          const int col = (h0 + hh) * 64 + dt * 16 + lo16;
          pb[(size_t)row * D_ + col] = f2b(acc[hh][qgg][dt][r]);
        }
}

// ---------- (x [+ y]) -> LayerNorm (D=1024, one block per row) ----------
__device__ __forceinline__ float block_sum(float vv, float* sm) {
#pragma unroll
  for (int o = 32; o > 0; o >>= 1) vv += __shfl_down(vv, o);
  __syncthreads();
  if ((threadIdx.x & 63) == 0) sm[threadIdx.x >> 6] = vv;
  __syncthreads();
  return sm[0] + sm[1] + sm[2] + sm[3];
}

// out fp32; AUX additionally writes bf16 copy (feeds next GEMM's A)
template<bool HAS_Y, bool AUX>
__global__ __launch_bounds__(256)
void add_ln(const float* __restrict__ x, const u16* __restrict__ y,
            const float* __restrict__ g, const float* __restrict__ bta,
            float* __restrict__ out, u16* __restrict__ aux)
{
  __shared__ float sm[4];
  const int row = blockIdx.x;
  const int t   = threadIdx.x;
  const size_t base = (size_t)row * D_ + t * 4;

  float s[4];
  load4(x + base, s);
  if (HAS_Y) {
    float yv[4];
    load4(y + base, yv);
    s[0] += yv[0]; s[1] += yv[1]; s[2] += yv[2]; s[3] += yv[3];
  }

  float loc = s[0] + s[1] + s[2] + s[3];
  float tot = block_sum(loc, sm);
  float mean = tot * (1.f / 1024.f);
  float d0 = s[0] - mean, d1 = s[1] - mean, d2 = s[2] - mean, d3 = s[3] - mean;
  float sq = d0 * d0 + d1 * d1 + d2 * d2 + d3 * d3;
  float tv = block_sum(sq, sm);
  float rstd = rsqrtf(tv * (1.f / 1024.f) + 1e-5f);

  float4 gv = *(const float4*)(g + t * 4);
  float4 bv = *(const float4*)(bta + t * 4);
  float o0 = d0 * rstd * gv.x + bv.x;
  float o1 = d1 * rstd * gv.y + bv.y;
  float o2 = d2 * rstd * gv.z + bv.z;
  float o3 = d3 * rstd * gv.w + bv.w;
  *(float4*)(out + base) = make_float4(o0, o1, o2, o3);
  if (AUX) {
    uint2 ov;
    ov.x = (u32)f2b(o0) | ((u32)f2b(o1) << 16);
    ov.y = (u32)f2b(o2) | ((u32)f2b(o3) << 16);
    *(uint2*)(aux + base) = ov;
  }
}

// ---------- launch ----------
// ws = 32 MiB exactly; d_out (16 MiB fp32) doubles as scratch.
// Schedule / lifetimes (MiB offsets into ws):
//   phase QKV : xb=d_out bf16(x); wqkvt@24..30; qkv@0..24 [4096][3072]
//   phase attn: vt@24..32 (wqkvt dead); partials = d_out (2 x 8MiB bf16)
//   merge     : ctx_b@0..8 (qkv dead)
//   phase proj: wot@16..18, ao@8..16
//   phase LN1 : x1=d_out fp32 (partials dead), x1b@0..8 (ctx_b dead)
//   phase FFN : w1t@8..12, w2t@12..16, h1@16..32 (two DFF halves)
extern "C" void kernel_launch(void* const* d_in, const int* in_sizes, int n_in,
                              void* d_out, int out_size, void* d_ws, size_t ws_size,
                              hipStream_t stream) {
  const float* x     = (const float*)d_in[0];
  const float* wq    = (const float*)d_in[1];
  const float* bq    = (const float*)d_in[2];
  const float* wk    = (const float*)d_in[3];
  const float* bk    = (const float*)d_in[4];
  const float* wv    = (const float*)d_in[5];
  const float* bv    = (const float*)d_in[6];
  const float* wo    = (const float*)d_in[7];
  const float* bo    = (const float*)d_in[8];
  const float* g1    = (const float*)d_in[9];
  const float* beta1 = (const float*)d_in[10];
  const float* w1    = (const float*)d_in[11];
  const float* b1    = (const float*)d_in[12];
  const float* w2    = (const float*)d_in[13];
  const float* b2    = (const float*)d_in[14];
  const float* g2    = (const float*)d_in[15];
  const float* beta2 = (const float*)d_in[16];
  float* outF = (float*)d_out;

  char* wsb = (char*)d_ws;
  const size_t MiB = (size_t)1 << 20;
  u16* qkv   = (u16*)(wsb + 0);
  u16* wqkvt = (u16*)(wsb + 24 * MiB);
  u16* vt    = (u16*)(wsb + 24 * MiB);
  u16* ctx_b = (u16*)(wsb + 0);
  u16* ao    = (u16*)(wsb + 8 * MiB);
  u16* wot   = (u16*)(wsb + 16 * MiB);
  u16* x1b   = (u16*)(wsb + 0);
  u16* w1t   = (u16*)(wsb + 8 * MiB);
  u16* w2t   = (u16*)(wsb + 12 * MiB);
  u16* h1    = (u16*)(wsb + 16 * MiB);
  u16* xb    = (u16*)d_out;
  u16* part  = (u16*)d_out;   // 2 x [4096][1024] bf16 partial ctx
  float* x1  = outF;
  float* z   = outF;

  dim3 blk(256);
  // x -> bf16 (into d_out scratch)
  cvt_f2b<<<dim3((M_ * D_) / (256 * 8)), blk, 0, stream>>>(x, xb);
  // weight transposes for fused QKV
  transpose_f2b<<<dim3(16, 16), blk, 0, stream>>>(wq, wqkvt,                 D_, D_);
  transpose_f2b<<<dim3(16, 16), blk, 0, stream>>>(wk, wqkvt + 1024 * 1024,   D_, D_);
  transpose_f2b<<<dim3(16, 16), blk, 0, stream>>>(wv, wqkvt + 2048 * 1024,   D_, D_);
  // fused QKV GEMM: [4096][3072], q-segment scaled by 0.125
  gemm_bf16<128, false, false, true, true, u16><<<dim3(QKV_LD / 128, M_ / 128), blk, 0, stream>>>(
      xb, wqkvt, bq, bk, bv, nullptr, qkv, M_, QKV_LD, D_);
  // Vt = V^T (V = qkv cols [2048,3072), row stride 3072)
  transpose_bf16<<<dim3(M_ / 64, 1024 / 64), blk, 0, stream>>>(qkv + 2048, vt, QKV_LD, M_);
  // attention v6 -> bf16 partials in d_out
  attention_mfma<<<dim3(256), dim3(512), 0, stream>>>(qkv, qkv + 1024, vt, part);
  // merge partials -> ctx_b (qkv dead)
  merge_b16<<<dim3((M_ * D_) / (256 * 8)), blk, 0, stream>>>(part, part + (size_t)M_ * D_, ctx_b);
  // output projection (BM=64 -> grid 512, 2 blocks/CU)
  transpose_f2b<<<dim3(16, 16), blk, 0, stream>>>(wo, wot, D_, D_);
  gemm_bf16<64, false, false, true, false, u16><<<dim3(D_ / 128, M_ / 64), blk, 0, stream>>>(
      ctx_b, wot, bo, nullptr, nullptr, nullptr, ao, M_, D_, D_);
  // x1 = LN(x + attn_out), fp32 to d_out + bf16 aux
  add_ln<true, true><<<dim3(M_), blk, 0, stream>>>(x, ao, g1, beta1, x1, x1b);
  // FFN in two DFF halves (h1 half = 16 MiB)
  transpose_f2b<<<dim3(16, 32), blk, 0, stream>>>(w1, w1t, DFF_, D_);
  transpose_f2b<<<dim3(32, 16), blk, 0, stream>>>(w2, w2t, D_, 2048);
  gemm_bf16<128, true, false, true, false, u16><<<dim3(2048 / 128, M_ / 128), blk, 0, stream>>>(
      x1b, w1t, b1, nullptr, nullptr, nullptr, h1, M_, 2048, D_);
  gemm_bf16<64, false, true, false, false, float><<<dim3(D_ / 128, M_ / 64), blk, 0, stream>>>(
      h1, w2t, nullptr, nullptr, nullptr, x1, z, M_, D_, 2048);
  transpose_f2b<<<dim3(16, 32), blk, 0, stream>>>(w1 + 2048, w1t, DFF_, D_);
  transpose_f2b<<<dim3(32, 16), blk, 0, stream>>>(w2 + (size_t)2048 * 1024, w2t, D_, 2048);
  gemm_bf16<128, true, false, true, false, u16><<<dim3(2048 / 128, M_ / 128), blk, 0, stream>>>(
      x1b, w1t, b1 + 2048, nullptr, nullptr, nullptr, h1, M_, 2048, D_);
  gemm_bf16<64, false, true, true, false, float><<<dim3(D_ / 128, M_ / 64), blk, 0, stream>>>(
      h1, w2t, b2, nullptr, nullptr, z, z, M_, D_, 2048);
  // out = LN(z), in-place on d_out
  add_ln<false, false><<<dim3(M_), blk, 0, stream>>>(z, nullptr, g2, beta2, outF, nullptr);
}

// Round 9
// 570.966 us; speedup vs baseline: 1.2791x; 1.2791x over previous
//
#include <hip/hip_runtime.h>
#include <stdint.h>

// Problem constants
#define B_   2
#define S_   2048
#define D_   1024
#define H_   16
#define DK_  64
#define DFF_ 4096
#define M_   (B_ * S_)   // 4096 rows total
#define QKV_LD 3072      // fused qkv row stride

typedef unsigned short u16;
typedef unsigned int   u32;
typedef __attribute__((ext_vector_type(8))) short short8;  // 8 bf16 (4 VGPRs)
typedef __attribute__((ext_vector_type(4))) float f32x4;   // MFMA C/D

// ---------- bf16 <-> f32 helpers ----------
__device__ __forceinline__ float b2f(u16 u) {
  union { u32 i; float f; } z; z.i = ((u32)u) << 16; return z.f;
}
__device__ __forceinline__ u16 f2b(float f) {
  union { float f; u32 i; } z; z.f = f;
  u32 x = z.i;
  u32 r = (x + 0x7fffu + ((x >> 16) & 1u)) >> 16;
  return (u16)r;
}
__device__ __forceinline__ void load4(const float* p, float* f) {
  float4 v = *(const float4*)p;
  f[0] = v.x; f[1] = v.y; f[2] = v.z; f[3] = v.w;
}
__device__ __forceinline__ void load4(const u16* p, float* f) {
  uint2 v = *(const uint2*)p;
  f[0] = b2f(v.x & 0xffffu); f[1] = b2f(v.x >> 16);
  f[2] = b2f(v.y & 0xffffu); f[3] = b2f(v.y >> 16);
}
__device__ __forceinline__ void tstore(float* p, float v) { *p = v; }
__device__ __forceinline__ void tstore(u16* p, float v)   { *p = f2b(v); }

// async global->LDS, 16 B per lane (dest = wave-uniform base + lane*16)
__device__ __forceinline__ void gld_lds16(const void* g, void* l) {
  __builtin_amdgcn_global_load_lds(
      (const __attribute__((address_space(1))) void*)g,
      (__attribute__((address_space(3))) void*)l, 16, 0, 0);
}

// ---------- m97-style MFMA GEMM: C = (A @ Wt^T + bias)*osc (+ReLU)(+res) ----
// A: bf16 [M][K] k-contig. Wt: bf16 [N][K] k-contig (pre-transposed weight).
// Tile BM x 128, BK=32, 256 threads = 4 waves (2x2), wave tile (BM/2) x 64.
// MFMA layouts: A[m=lane&15][k=quad*8+j], B[n=lane&15][k=quad*8+j],
// D[row=quad*4+r][col=lane&15].
// QKV=true: N spans 3 weight segments of 1024; per-block bias/scale select;
// bias indexed with SEGMENT-LOCAL column (col0 & 1023).
template<int BM, bool RELU, bool RES, bool BIAS, bool QKV, typename TO>
__global__ __launch_bounds__(256)
void gemm_bf16(const u16* __restrict__ A, const u16* __restrict__ Wt,
               const float* __restrict__ bias0, const float* __restrict__ bias1,
               const float* __restrict__ bias2, const float* __restrict__ res,
               TO* __restrict__ C, int M, int N, int K)
{
  constexpr int WM = BM / 2;     // wave M extent
  constexpr int MI = WM / 16;    // A-frags per wave (4 or 2)
  __shared__ u16 As[BM][32];
  __shared__ u16 Bs[128][32];

  const int tid  = threadIdx.x;
  const int wave = tid >> 6;
  const int lane = tid & 63;
  const int lo16 = lane & 15;
  const int quad = lane >> 4;
  const int row0 = blockIdx.y * BM;
  const int col0 = blockIdx.x * 128;
  const int mb   = (wave & 1) * WM;
  const int nb   = (wave >> 1) * 64;

  const float* bias = bias0;
  float osc = 1.0f;
  if (QKV) {
    const int seg = col0 >> 10;              // block fully inside one segment
    bias = (seg == 0) ? bias0 : (seg == 1 ? bias1 : bias2);
    if (seg == 0) osc = 0.125f;              // 1/sqrt(dk) folded into q
  }
  const int bc0 = QKV ? (col0 & 1023) : col0;  // segment-local bias column

  f32x4 acc[MI][4];
#pragma unroll
  for (int i = 0; i < MI; ++i)
#pragma unroll
    for (int j = 0; j < 4; ++j) acc[i][j] = (f32x4){0.f, 0.f, 0.f, 0.f};

  const int s_row = tid >> 2;          // 0..63
  const int s_ch  = (tid & 3) * 8;     // bf16 elems
  const u16* gA = A  + (size_t)(row0 + s_row) * K + s_ch;
  const u16* gB = Wt + (size_t)(col0 + s_row) * K + s_ch;

  for (int k0 = 0; k0 < K; k0 += 32) {
    gld_lds16(gA, &As[s_row][s_ch]);
    if constexpr (BM == 128)
      gld_lds16(gA + (size_t)64 * K, &As[s_row + (BM == 128 ? 64 : 0)][s_ch]);
    gld_lds16(gB, &Bs[s_row][s_ch]);
    gld_lds16(gB + (size_t)64 * K, &Bs[s_row + 64][s_ch]);
    gA += 32; gB += 32;
    __syncthreads();

    short8 af[MI], bf[4];
#pragma unroll
    for (int mi = 0; mi < MI; ++mi)
      af[mi] = *(const short8*)&As[mb + mi * 16 + lo16][quad * 8];
#pragma unroll
    for (int ni = 0; ni < 4; ++ni)
      bf[ni] = *(const short8*)&Bs[nb + ni * 16 + lo16][quad * 8];
#pragma unroll
    for (int mi = 0; mi < MI; ++mi)
#pragma unroll
      for (int ni = 0; ni < 4; ++ni)
        acc[mi][ni] = __builtin_amdgcn_mfma_f32_16x16x32_bf16(af[mi], bf[ni], acc[mi][ni], 0, 0, 0);
    __syncthreads();
  }

  // epilogue
  float bv[4];
#pragma unroll
  for (int ni = 0; ni < 4; ++ni)
    bv[ni] = BIAS ? bias[bc0 + nb + ni * 16 + lo16] : 0.f;
#pragma unroll
  for (int mi = 0; mi < MI; ++mi) {
#pragma unroll
    for (int ni = 0; ni < 4; ++ni) {
      const int col = col0 + nb + ni * 16 + lo16;
#pragma unroll
      for (int r = 0; r < 4; ++r) {
        const int row = row0 + mb + mi * 16 + quad * 4 + r;
        float vv = (acc[mi][ni][r] + bv[ni]) * osc;
        if (RELU) vv = fmaxf(vv, 0.f);
        if (RES)  vv += res[(size_t)row * N + col];
        tstore(C + (size_t)row * N + col, vv);
      }
    }
  }
}

// ---------- elementwise fp32 -> bf16 ----------
__global__ __launch_bounds__(256)
void cvt_f2b(const float* __restrict__ in, u16* __restrict__ out)
{
  const size_t i = ((size_t)blockIdx.x * 256 + threadIdx.x) * 8;
  float4 a = *(const float4*)(in + i);
  float4 b = *(const float4*)(in + i + 4);
  uint4 o;
  o.x = (u32)f2b(a.x) | ((u32)f2b(a.y) << 16);
  o.y = (u32)f2b(a.z) | ((u32)f2b(a.w) << 16);
  o.z = (u32)f2b(b.x) | ((u32)f2b(b.y) << 16);
  o.w = (u32)f2b(b.z) | ((u32)f2b(b.w) << 16);
  *(uint4*)(out + i) = o;
}

// ---------- bf16 partial merge: out = p0 + p1 (bf16) ----------
__global__ __launch_bounds__(256)
void merge_b16(const u16* __restrict__ p0, const u16* __restrict__ p1,
               u16* __restrict__ out)
{
  const size_t i = ((size_t)blockIdx.x * 256 + threadIdx.x) * 8;
  uint4 a = *(const uint4*)(p0 + i);
  uint4 b = *(const uint4*)(p1 + i);
  uint4 o;
  const u32* ap = (const u32*)&a;
  const u32* bp = (const u32*)&b;
  u32* op = (u32*)&o;
#pragma unroll
  for (int j = 0; j < 4; ++j) {
    float lo = b2f((u16)(ap[j] & 0xffffu)) + b2f((u16)(bp[j] & 0xffffu));
    float hi = b2f((u16)(ap[j] >> 16))     + b2f((u16)(bp[j] >> 16));
    op[j] = (u32)f2b(lo) | ((u32)f2b(hi) << 16);
  }
  *(uint4*)(out + i) = o;
}

// ---------- fp32 [R][C] -> bf16 transposed [C][R] (64x64 tiles) ----------
__global__ __launch_bounds__(256)
void transpose_f2b(const float* __restrict__ in, u16* __restrict__ out,
                   int ld_in, int ld_out)
{
  __shared__ u16 tile[64][68];
  const int t  = threadIdx.x;
  const int r0 = blockIdx.x * 64;
  const int c0 = blockIdx.y * 64;
  const int rr = t >> 4;            // 0..15
  const int cc = (t & 15) * 4;      // 0..60
#pragma unroll
  for (int rep = 0; rep < 4; ++rep) {
    float4 v = *(const float4*)(in + (size_t)(r0 + rr + rep * 16) * ld_in + c0 + cc);
    tile[rr + rep * 16][cc + 0] = f2b(v.x);
    tile[rr + rep * 16][cc + 1] = f2b(v.y);
    tile[rr + rep * 16][cc + 2] = f2b(v.z);
    tile[rr + rep * 16][cc + 3] = f2b(v.w);
  }
  __syncthreads();
#pragma unroll
  for (int rep = 0; rep < 4; ++rep) {
    const int dr = rr + rep * 16;   // local c
    uint2 o;
    o.x = (u32)tile[cc + 0][dr] | ((u32)tile[cc + 1][dr] << 16);
    o.y = (u32)tile[cc + 2][dr] | ((u32)tile[cc + 3][dr] << 16);
    *(uint2*)(out + (size_t)(c0 + dr) * ld_out + r0 + cc) = o;
  }
}

// ---------- bf16 transpose with strides (for V -> Vt) ----------
__global__ __launch_bounds__(256)
void transpose_bf16(const u16* __restrict__ in, u16* __restrict__ out,
                    int ld_in, int ld_out)
{
  __shared__ u16 tile[64][68];
  const int t  = threadIdx.x;
  const int r0 = blockIdx.x * 64;   // token dim
  const int c0 = blockIdx.y * 64;   // feature dim
  const int rr = t >> 4;
  const int cc = (t & 15) * 4;
#pragma unroll
  for (int rep = 0; rep < 4; ++rep) {
    uint2 vv = *(const uint2*)(in + (size_t)(r0 + rr + rep * 16) * ld_in + c0 + cc);
    *(uint2*)&tile[rr + rep * 16][cc] = vv;
  }
  __syncthreads();
#pragma unroll
  for (int rep = 0; rep < 4; ++rep) {
    const int dr = rr + rep * 16;
    uint2 o;
    o.x = (u32)tile[cc + 0][dr] | ((u32)tile[cc + 1][dr] << 16);
    o.y = (u32)tile[cc + 2][dr] | ((u32)tile[cc + 3][dr] << 16);
    *(uint2*)(out + (size_t)(c0 + dr) * ld_out + r0 + cc) = o;
  }
}

// scale a bf16x8 fragment elementwise by rv[0..7] (f32), repack bf16 (RHU)
__device__ __forceinline__ short8 scale8(short8 a, f32x4 r0, f32x4 r1) {
  const u32* ap = (const u32*)&a;
  short8 o;
  u32* op = (u32*)&o;
#pragma unroll
  for (int i = 0; i < 4; ++i) {
    union { u32 u; float f; } lo, hi;
    lo.u = ap[i] << 16;
    hi.u = ap[i] & 0xffff0000u;
    float rl = (i < 2) ? r0[2 * i]     : r1[2 * i - 4];
    float rh = (i < 2) ? r0[2 * i + 1] : r1[2 * i - 3];
    lo.f *= rl;
    hi.f *= rh;
    op[i] = ((lo.u + 0x8000u) >> 16) | ((hi.u + 0x8000u) & 0xffff0000u);
  }
  return o;
}

// ---------- MFMA attention v7: v4 structure + Q in LDS (frees 128 VGPR) ----
// Round-6 v4 geometry (best, 242 us): grid 256 = 4 groups (batch x t-half)
// x 64 q-tiles, 512 thr (8 waves), 1 block/CU, QBLK=32, 2 barriers/step.
// v4's limiter (diagnosed via v6's spill disaster): qf[32] hogs 128 VGPR,
// leaving the compiler no registers to keep K/Vt L2 loads in flight ->
// ~400-cyc load chains serialized (MfmaUtil 5.7%). v7 moves Q to LDS:
//   Qs[32][1024] bf16 = 64 KB, b128-chunk XOR swizzle (chunk ^= row&7):
//   phase-A read lanes hit 8 distinct chunks x 2 rows = 2-way conflict
//   (free, m136). Phase A reads Q via ds_read_b128 (~cheap), K via global;
//   freed VGPRs let the compiler pipeline the 32 independent K loads.
// Math bit-identical to v4: unnormalized-exp softmax (|S|<~3), Ws/Rs
// swizzle pos = t ^ ((q&7)<<3), scale8 normalize in phase B.
// LDS = 64 + 64 + 8 = 136 KB.
__global__ __launch_bounds__(512, 2)
void attention_mfma(const u16* __restrict__ q, const u16* __restrict__ k,
                    const u16* __restrict__ vt, u16* __restrict__ partial)
{
  __shared__ __align__(16) u16 Qs[32][1024];     // 65,536 B (Q, swizzled)
  __shared__ __align__(16) u16 Ws[16][32][64];   // 65,536 B (e, bf16)
  __shared__ __align__(16) float Rs[32][64];     //  8,192 B (rinv, f32)

  const int tid  = threadIdx.x;
  const int wave = tid >> 6;
  const int lane = tid & 63;
  const int lo16 = lane & 15;
  const int quad = lane >> 4;

  const int p     = blockIdx.x;
  const int g     = (p & 7) >> 1;          // group: batch x t-half
  const int batch = g >> 1;
  const int half  = g & 1;
  const int qt    = ((p >> 3) << 1) | (p & 1);   // 0..63
  const int qrow0 = batch * S_ + qt * 32;
  const int tbase = half * 1024;

  const int qg = wave >> 2;                // 0..1: q-group (16 rows)
  const int tg = wave & 3;                 // 0..3: t-group (16 tokens)
  const int h0 = wave * 2;                 // phase-B heads

  // ---- stage Q tile into LDS (one-time, coalesced, swizzled) ----
  {
    const int r  = tid >> 4;               // 0..31
    const int c0 = tid & 15;               // 0..15
    const u16* grow = q + (size_t)(qrow0 + r) * QKV_LD;
    const int swz = r & 7;
#pragma unroll
    for (int i = 0; i < 8; ++i) {
      const int ch = c0 + i * 16;          // b128 chunk 0..127
      uint4 v = *(const uint4*)(grow + ch * 8);
      *(uint4*)&Qs[r][(ch ^ swz) * 8] = v;
    }
  }

  f32x4 acc[2][2][4];                      // [hh][qg][dt]
#pragma unroll
  for (int a = 0; a < 2; ++a)
#pragma unroll
    for (int b = 0; b < 2; ++b)
#pragma unroll
      for (int c = 0; c < 4; ++c) acc[a][b][c] = (f32x4){0.f, 0.f, 0.f, 0.f};

  const u16* kbase  = k + (size_t)(batch * S_ + tbase + tg * 16 + lo16) * QKV_LD + quad * 8;
  const u16* vbase0 = vt + (size_t)batch * S_ + tbase + quad * 8;

  // phase-A row/slot constants
  const int qr  = qg * 16 + lo16;          // this lane's q-row in Qs
  const int qsw = qr & 7;
  int pos_r[4], qabs_r[4];
#pragma unroll
  for (int r = 0; r < 4; ++r) {
    qabs_r[r] = qg * 16 + quad * 4 + r;
    pos_r[r]  = (tg * 16 + lo16) ^ ((qabs_r[r] & 7) << 3);
  }

  __syncthreads();   // Qs ready

  for (int s = 0; s < 16; ++s) {
    // ---- phase A: e = exp(scores), denom, write Ws/Rs ----
    {
      const u16* krow = kbase + (size_t)(s * 64) * QKV_LD;
      float ssum[4] = {0.f, 0.f, 0.f, 0.f};
#pragma unroll
      for (int h = 0; h < 16; ++h) {
        short8 b0 = *(const short8*)(krow + h * 64);
        short8 b1 = *(const short8*)(krow + h * 64 + 32);
        short8 a0 = *(const short8*)&Qs[qr][((h * 8 + quad) ^ qsw) * 8];
        short8 a1 = *(const short8*)&Qs[qr][((h * 8 + 4 + quad) ^ qsw) * 8];
        f32x4 sg = (f32x4){0.f, 0.f, 0.f, 0.f};
        sg = __builtin_amdgcn_mfma_f32_16x16x32_bf16(a0, b0, sg, 0, 0, 0);
        sg = __builtin_amdgcn_mfma_f32_16x16x32_bf16(a1, b1, sg, 0, 0, 0);
#pragma unroll
        for (int r = 0; r < 4; ++r) {
          union { float f; u32 u; } e;
          e.f = __expf(sg[r]);             // no max: |S| <~ 3 by construction
          ssum[r] += e.f;
          Ws[h][qabs_r[r]][pos_r[r]] = (u16)((e.u + 0x8000u) >> 16);
        }
      }
#pragma unroll
      for (int r = 0; r < 4; ++r)
        Rs[qabs_r[r]][pos_r[r]] = 1.0f / ssum[r];
    }
    __syncthreads();

    // ---- phase B: ctx += (e * rinv) @ V ----
#pragma unroll
    for (int kc = 0; kc < 2; ++kc) {
      const int ksw = (kc * 32 + quad * 8) ^ ((lo16 & 7) << 3);
      f32x4 rv0a = *(const f32x4*)&Rs[lo16][ksw];
      f32x4 rv0b = *(const f32x4*)&Rs[lo16][ksw + 4];
      f32x4 rv1a = *(const f32x4*)&Rs[16 + lo16][ksw];
      f32x4 rv1b = *(const f32x4*)&Rs[16 + lo16][ksw + 4];
#pragma unroll
      for (int hh = 0; hh < 2; ++hh) {
        short8 sw0 = scale8(*(const short8*)&Ws[h0 + hh][lo16][ksw],      rv0a, rv0b);
        short8 sw1 = scale8(*(const short8*)&Ws[h0 + hh][16 + lo16][ksw], rv1a, rv1b);
#pragma unroll
        for (int dt = 0; dt < 4; ++dt) {
          short8 bv = *(const short8*)(vbase0 +
              (size_t)((h0 + hh) * 64 + dt * 16 + lo16) * M_ + s * 64 + kc * 32);
          acc[hh][0][dt] = __builtin_amdgcn_mfma_f32_16x16x32_bf16(sw0, bv, acc[hh][0][dt], 0, 0, 0);
          acc[hh][1][dt] = __builtin_amdgcn_mfma_f32_16x16x32_bf16(sw1, bv, acc[hh][1][dt], 0, 0, 0);
        }
      }
    }
    __syncthreads();
  }

  // epilogue: bf16 partial ctx (each element written by exactly one block)
  u16* pb = partial + (size_t)half * M_ * D_;
#pragma unroll
  for (int hh = 0; hh < 2; ++hh)
#pragma unroll
    for (int qgg = 0; qgg < 2; ++qgg)
#pragma unroll
      for (int dt = 0; dt < 4; ++dt)
#pragma unroll
        for (int r = 0; r < 4; ++r) {
          const int row = qrow0 + qgg * 16 + quad * 4 + r;
          const int col = (h0 + hh) * 64 + dt * 16 + lo16;
          pb[(size_t)row * D_ + col] = f2b(acc[hh][qgg][dt][r]);
        }
}

// ---------- (x [+ y]) -> LayerNorm (D=1024, one block per row) ----------
__device__ __forceinline__ float block_sum(float vv, float* sm) {
#pragma unroll
  for (int o = 32; o > 0; o >>= 1) vv += __shfl_down(vv, o);
  __syncthreads();
  if ((threadIdx.x & 63) == 0) sm[threadIdx.x >> 6] = vv;
  __syncthreads();
  return sm[0] + sm[1] + sm[2] + sm[3];
}

// out fp32; AUX additionally writes bf16 copy (feeds next GEMM's A)
template<bool HAS_Y, bool AUX>
__global__ __launch_bounds__(256)
void add_ln(const float* __restrict__ x, const u16* __restrict__ y,
            const float* __restrict__ g, const float* __restrict__ bta,
            float* __restrict__ out, u16* __restrict__ aux)
{
  __shared__ float sm[4];
  const int row = blockIdx.x;
  const int t   = threadIdx.x;
  const size_t base = (size_t)row * D_ + t * 4;

  float s[4];
  load4(x + base, s);
  if (HAS_Y) {
    float yv[4];
    load4(y + base, yv);
    s[0] += yv[0]; s[1] += yv[1]; s[2] += yv[2]; s[3] += yv[3];
  }

  float loc = s[0] + s[1] + s[2] + s[3];
  float tot = block_sum(loc, sm);
  float mean = tot * (1.f / 1024.f);
  float d0 = s[0] - mean, d1 = s[1] - mean, d2 = s[2] - mean, d3 = s[3] - mean;
  float sq = d0 * d0 + d1 * d1 + d2 * d2 + d3 * d3;
  float tv = block_sum(sq, sm);
  float rstd = rsqrtf(tv * (1.f / 1024.f) + 1e-5f);

  float4 gv = *(const float4*)(g + t * 4);
  float4 bv = *(const float4*)(bta + t * 4);
  float o0 = d0 * rstd * gv.x + bv.x;
  float o1 = d1 * rstd * gv.y + bv.y;
  float o2 = d2 * rstd * gv.z + bv.z;
  float o3 = d3 * rstd * gv.w + bv.w;
  *(float4*)(out + base) = make_float4(o0, o1, o2, o3);
  if (AUX) {
    uint2 ov;
    ov.x = (u32)f2b(o0) | ((u32)f2b(o1) << 16);
    ov.y = (u32)f2b(o2) | ((u32)f2b(o3) << 16);
    *(uint2*)(aux + base) = ov;
  }
}

// ---------- launch ----------
// ws = 32 MiB exactly; d_out (16 MiB fp32) doubles as scratch.
// Schedule / lifetimes (MiB offsets into ws):
//   phase QKV : xb=d_out bf16(x); wqkvt@24..30; qkv@0..24 [4096][3072]
//   phase attn: vt@24..32 (wqkvt dead); partials = d_out (2 x 8MiB bf16)
//   merge     : ctx_b@0..8 (qkv dead)
//   phase proj: wot@16..18, ao@8..16
//   phase LN1 : x1=d_out fp32 (partials dead), x1b@0..8 (ctx_b dead)
//   phase FFN : w1t@8..12, w2t@12..16, h1@16..32 (two DFF halves)
extern "C" void kernel_launch(void* const* d_in, const int* in_sizes, int n_in,
                              void* d_out, int out_size, void* d_ws, size_t ws_size,
                              hipStream_t stream) {
  const float* x     = (const float*)d_in[0];
  const float* wq    = (const float*)d_in[1];
  const float* bq    = (const float*)d_in[2];
  const float* wk    = (const float*)d_in[3];
  const float* bk    = (const float*)d_in[4];
  const float* wv    = (const float*)d_in[5];
  const float* bv    = (const float*)d_in[6];
  const float* wo    = (const float*)d_in[7];
  const float* bo    = (const float*)d_in[8];
  const float* g1    = (const float*)d_in[9];
  const float* beta1 = (const float*)d_in[10];
  const float* w1    = (const float*)d_in[11];
  const float* b1    = (const float*)d_in[12];
  const float* w2    = (const float*)d_in[13];
  const float* b2    = (const float*)d_in[14];
  const float* g2    = (const float*)d_in[15];
  const float* beta2 = (const float*)d_in[16];
  float* outF = (float*)d_out;

  char* wsb = (char*)d_ws;
  const size_t MiB = (size_t)1 << 20;
  u16* qkv   = (u16*)(wsb + 0);
  u16* wqkvt = (u16*)(wsb + 24 * MiB);
  u16* vt    = (u16*)(wsb + 24 * MiB);
  u16* ctx_b = (u16*)(wsb + 0);
  u16* ao    = (u16*)(wsb + 8 * MiB);
  u16* wot   = (u16*)(wsb + 16 * MiB);
  u16* x1b   = (u16*)(wsb + 0);
  u16* w1t   = (u16*)(wsb + 8 * MiB);
  u16* w2t   = (u16*)(wsb + 12 * MiB);
  u16* h1    = (u16*)(wsb + 16 * MiB);
  u16* xb    = (u16*)d_out;
  u16* part  = (u16*)d_out;   // 2 x [4096][1024] bf16 partial ctx
  float* x1  = outF;
  float* z   = outF;

  dim3 blk(256);
  // x -> bf16 (into d_out scratch)
  cvt_f2b<<<dim3((M_ * D_) / (256 * 8)), blk, 0, stream>>>(x, xb);
  // weight transposes for fused QKV
  transpose_f2b<<<dim3(16, 16), blk, 0, stream>>>(wq, wqkvt,                 D_, D_);
  transpose_f2b<<<dim3(16, 16), blk, 0, stream>>>(wk, wqkvt + 1024 * 1024,   D_, D_);
  transpose_f2b<<<dim3(16, 16), blk, 0, stream>>>(wv, wqkvt + 2048 * 1024,   D_, D_);
  // fused QKV GEMM: [4096][3072], q-segment scaled by 0.125
  gemm_bf16<128, false, false, true, true, u16><<<dim3(QKV_LD / 128, M_ / 128), blk, 0, stream>>>(
      xb, wqkvt, bq, bk, bv, nullptr, qkv, M_, QKV_LD, D_);
  // Vt = V^T (V = qkv cols [2048,3072), row stride 3072)
  transpose_bf16<<<dim3(M_ / 64, 1024 / 64), blk, 0, stream>>>(qkv + 2048, vt, QKV_LD, M_);
  // attention v7 -> bf16 partials in d_out
  attention_mfma<<<dim3(256), dim3(512), 0, stream>>>(qkv, qkv + 1024, vt, part);
  // merge partials -> ctx_b (qkv dead)
  merge_b16<<<dim3((M_ * D_) / (256 * 8)), blk, 0, stream>>>(part, part + (size_t)M_ * D_, ctx_b);
  // output projection (BM=64 -> grid 512, 2 blocks/CU)
  transpose_f2b<<<dim3(16, 16), blk, 0, stream>>>(wo, wot, D_, D_);
  gemm_bf16<64, false, false, true, false, u16><<<dim3(D_ / 128, M_ / 64), blk, 0, stream>>>(
      ctx_b, wot, bo, nullptr, nullptr, nullptr, ao, M_, D_, D_);
  // x1 = LN(x + attn_out), fp32 to d_out + bf16 aux
  add_ln<true, true><<<dim3(M_), blk, 0, stream>>>(x, ao, g1, beta1, x1, x1b);
  // FFN in two DFF halves (h1 half = 16 MiB)
  transpose_f2b<<<dim3(16, 32), blk, 0, stream>>>(w1, w1t, DFF_, D_);
  transpose_f2b<<<dim3(32, 16), blk, 0, stream>>>(w2, w2t, D_, 2048);
  gemm_bf16<128, true, false, true, false, u16><<<dim3(2048 / 128, M_ / 128), blk, 0, stream>>>(
      x1b, w1t, b1, nullptr, nullptr, nullptr, h1, M_, 2048, D_);
  gemm_bf16<64, false, true, false, false, float><<<dim3(D_ / 128, M_ / 64), blk, 0, stream>>>(
      h1, w2t, nullptr, nullptr, nullptr, x1, z, M_, D_, 2048);
  transpose_f2b<<<dim3(16, 32), blk, 0, stream>>>(w1 + 2048, w1t, DFF_, D_);
  transpose_f2b<<<dim3(32, 16), blk, 0, stream>>>(w2 + (size_t)2048 * 1024, w2t, D_, 2048);
  gemm_bf16<128, true, false, true, false, u16><<<dim3(2048 / 128, M_ / 128), blk, 0, stream>>>(
      x1b, w1t, b1 + 2048, nullptr, nullptr, nullptr, h1, M_, 2048, D_);
  gemm_bf16<64, false, true, true, false, float><<<dim3(D_ / 128, M_ / 64), blk, 0, stream>>>(
      h1, w2t, b2, nullptr, nullptr, z, z, M_, D_, 2048);
  // out = LN(z), in-place on d_out
  add_ln<false, false><<<dim3(M_), blk, 0, stream>>>(z, nullptr, g2, beta2, outF, nullptr);
}